// Round 3
// baseline (83.062 us; speedup 1.0000x reference)
//
#include <hip/hip_runtime.h>

typedef float v2f __attribute__((ext_vector_type(2)));

#define MPTS 8192      // pc points per batch
#define NVERT 8192     // mesh vertices per batch
#define TPB 256
#define PPT 8          // points per thread
#define BQ (TPB*PPT)   // 2048 points per block
#define NCHUNK 32
#define VC (NVERT/NCHUNK)  // 256 vertices per chunk

// Kernel 1: per-point min of t = |v|^2 - 2 p.v over one 256-vertex chunk.
// Vertices are read with wave-uniform loads (scalar/K$ path — no LDS, no
// syncthreads). Inner math vectorized over vertex pairs so the backend can
// select v_pk_fma_f32: per point per 2 verts = 3 pk_fma + 2 v_min.
__global__ __launch_bounds__(TPB) void minpart_kernel(
        const float* __restrict__ vert,    // [B,3,NVERT]
        const float* __restrict__ pc,      // [B,3,MPTS]
        float* __restrict__ partial)       // [B,NCHUNK,MPTS]
{
    const int b = blockIdx.z, chunk = blockIdx.y;
    const int mbase = blockIdx.x * BQ;
    const int tid = threadIdx.x;

    // Per-thread point coefficients (-2p), splat into both float2 halves.
    const float* pcb = pc + (size_t)b * 3 * MPTS;
    v2f npx[PPT], npy[PPT], npz[PPT];
    #pragma unroll
    for (int p = 0; p < PPT; ++p) {
        const int m = mbase + p * TPB + tid;
        const float x = pcb[m], y = pcb[MPTS + m], z = pcb[2 * MPTS + m];
        npx[p] = (v2f){-2.0f * x, -2.0f * x};
        npy[p] = (v2f){-2.0f * y, -2.0f * y};
        npz[p] = (v2f){-2.0f * z, -2.0f * z};
    }

    // Wave-uniform vertex pointers for this chunk.
    const float* vb = vert + (size_t)b * 3 * NVERT + chunk * VC;
    const v2f* vbx = (const v2f*)(vb);
    const v2f* vby = (const v2f*)(vb + NVERT);
    const v2f* vbz = (const v2f*)(vb + 2 * NVERT);

    v2f acc[PPT];
    #pragma unroll
    for (int p = 0; p < PPT; ++p) acc[p] = (v2f){1e30f, 1e30f};

    #pragma unroll 4
    for (int j = 0; j < VC / 2; ++j) {
        const v2f vx = vbx[j], vy = vby[j], vz = vbz[j];
        const v2f vw = vx * vx + vy * vy + vz * vz;   // |v|^2, uniform, on VALU
        #pragma unroll
        for (int p = 0; p < PPT; ++p) {
            const v2f t = __builtin_elementwise_fma(npx[p], vx,
                           __builtin_elementwise_fma(npy[p], vy,
                            __builtin_elementwise_fma(npz[p], vz, vw)));
            acc[p] = __builtin_elementwise_min(acc[p], t);
        }
    }

    // One coalesced store per point — no atomics, no init required.
    float* po = partial + ((size_t)b * NCHUNK + chunk) * MPTS + mbase + tid;
    #pragma unroll
    for (int p = 0; p < PPT; ++p)
        po[p * TPB] = fminf(acc[p].x, acc[p].y);
}

// Kernel 2: fold the NCHUNK partial minima per point, add |p|^2, mask
// all-zero columns, per-block (sum,cnt) partials. 8 blocks per batch.
__global__ __launch_bounds__(256) void reduce_kernel(
        const float* __restrict__ pc,
        const float* __restrict__ partial,
        v2f* __restrict__ part)            // [B*8]
{
    const int b = blockIdx.x >> 3, sl = blockIdx.x & 7;
    const int tid = threadIdx.x;
    const float* pcb = pc + (size_t)b * 3 * MPTS;
    const float* pb  = partial + (size_t)b * NCHUNK * MPTS;

    float sum = 0.0f, cnt = 0.0f;
    #pragma unroll
    for (int k = 0; k < 4; ++k) {
        const int m = sl * 1024 + k * 256 + tid;
        float t = pb[m];
        #pragma unroll
        for (int c = 1; c < NCHUNK; ++c)
            t = fminf(t, pb[(size_t)c * MPTS + m]);     // coalesced per plane
        const float x = pcb[m], y = pcb[MPTS + m], z = pcb[2 * MPTS + m];
        const float d2 = fmaf(x, x, fmaf(y, y, fmaf(z, z, t)));
        if (!(x == 0.0f && y == 0.0f && z == 0.0f)) { sum += d2; cnt += 1.0f; }
    }
    for (int off = 32; off; off >>= 1) {
        sum += __shfl_down(sum, off);
        cnt += __shfl_down(cnt, off);
    }
    __shared__ float ss[4], sc[4];
    const int wid = tid >> 6, lane = tid & 63;
    if (lane == 0) { ss[wid] = sum; sc[wid] = cnt; }
    __syncthreads();
    if (tid == 0)
        part[blockIdx.x] = (v2f){ss[0] + ss[1] + ss[2] + ss[3],
                                 sc[0] + sc[1] + sc[2] + sc[3]};
}

// Kernel 3: one wave folds 8 partials per batch, then means across batches.
__global__ __launch_bounds__(64) void final_kernel(
        const v2f* __restrict__ part, float* __restrict__ out, int B)
{
    const int lane = threadIdx.x;
    float s = 0.0f, c = 0.0f;
    if (lane < B * 8) { const v2f p = part[lane]; s = p.x; c = p.y; }
    #pragma unroll
    for (int off = 4; off; off >>= 1) {
        s += __shfl_down(s, off);
        c += __shfl_down(c, off);
    }
    const float r = s / c;                 // valid at lane % 8 == 0
    float acc = 0.0f;
    for (int g = 0; g < B; ++g) acc += __shfl(r, g * 8);
    if (lane == 0) out[0] = acc / (float)B;
}

extern "C" void kernel_launch(void* const* d_in, const int* in_sizes, int n_in,
                              void* d_out, int out_size, void* d_ws, size_t ws_size,
                              hipStream_t stream) {
    const float* vert = (const float*)d_in[0];  // [B,3,128,64]
    const float* pc   = (const float*)d_in[1];  // [B,3,8192]
    float* out        = (float*)d_out;
    const int B = in_sizes[0] / (3 * NVERT);

    float* partial = (float*)d_ws;                               // [B,32,MPTS] = 4 MB
    v2f* part = (v2f*)(partial + (size_t)B * NCHUNK * MPTS);     // [B*8]

    dim3 grid(MPTS / BQ, NCHUNK, B);   // 4 x 32 x B = 512 blocks
    minpart_kernel<<<grid, TPB, 0, stream>>>(vert, pc, partial);
    reduce_kernel<<<B * 8, 256, 0, stream>>>(pc, partial, part);
    final_kernel<<<1, 64, 0, stream>>>(part, out, B);
}